// Round 7
// baseline (128.303 us; speedup 1.0000x reference)
//
#include <hip/hip_runtime.h>

// ---------------------------------------------------------------------------
// CVX_Reasoning_Engine — Round 18: back to 2 blocks/CU, keep all wins.
//   R16 profile: BM=64 (137KB LDS -> 1 block/CU, Occ 19%) ran 47-57 µs, WORSE
//   than R11's BM=32 (<42.6). Phase-serialized kernel (barriers, ring fills,
//   drains) with 1 block/CU has nothing to cover stalls — which is why DEP
//   and ILP levers were all neutral at ≤13% pipe busy. R18: BM=32, 512 thr
//   (8 waves, N-split 8-way, MR=2), R11's proven 68.6KB LDS layout ->
//   2 blocks/CU (16 waves/CU), plus tied drains (R15), de-clobbered vwait +
//   A-prefetch (R17). Accumulation order per column unchanged.
// ---------------------------------------------------------------------------

#define MROWS 16384

typedef __attribute__((ext_vector_type(8))) short bf16x8;   // 8 bf16 = 4 VGPRs
typedef __attribute__((ext_vector_type(4))) float floatx4;

__device__ __forceinline__ unsigned short f2bf(float x) {
    union { float f; unsigned u; } c; c.f = x;
    unsigned r = c.u + 0x7fffu + ((c.u >> 16) & 1u);   // RNE
    return (unsigned short)(r >> 16);
}
__device__ __forceinline__ float bf2f(unsigned short b) {
    union { unsigned u; float f; } c; c.u = ((unsigned)b) << 16;
    return c.f;
}

// --- invisible-to-compiler 16B global load (1 KB/wave) ----------------------
__device__ __forceinline__ bf16x8 gload(const unsigned short* p) {
    bf16x8 r;
    asm volatile("global_load_dwordx4 %0, %1, off"
                 : "=&v"(r)
                 : "v"((unsigned long long)(size_t)p)
                 : "memory");
    return r;
}
// wait until <=IMM vmem outstanding. NO memory clobber: the "+v" tie carries
// the real dependence; LDS reads may be hoisted above the stall. (R17-proven.)
template<int IMM>
__device__ __forceinline__ void vwait(bf16x8& v) {
    asm volatile("s_waitcnt vmcnt(%1)" : "+v"(v) : "n"(IMM));
}
// TIED drains: keep every ring register live until vmcnt(0) so regalloc
// cannot reassign a VGPR that an in-flight load will still write. (R15.)
__device__ __forceinline__ void drain8(bf16x8 (&r)[8]) {
    asm volatile("s_waitcnt vmcnt(0)"
                 : "+v"(r[0]), "+v"(r[1]), "+v"(r[2]), "+v"(r[3]),
                   "+v"(r[4]), "+v"(r[5]), "+v"(r[6]), "+v"(r[7])
                 :: "memory");
}
__device__ __forceinline__ void drain4(bf16x8 (&r)[4]) {
    asm volatile("s_waitcnt vmcnt(0)"
                 : "+v"(r[0]), "+v"(r[1]), "+v"(r[2]), "+v"(r[3])
                 :: "memory");
}

// ---- pack weights -> ks-major fragment-ordered bf16 ------------------------
// W1..W4: T[((ks*NT + ntile)*64 + quad*16 + m_l)*8 + e],  NT = N/16.
// W5: split hi/lo interleaved: T5[(((ks*16 + ntile)*2 + hl)*64 + ...)*8 + e].
__global__ __launch_bounds__(256) void pack_wt(
    const float* __restrict__ W1, unsigned short* __restrict__ T1,
    const float* __restrict__ W2, unsigned short* __restrict__ T2,
    const float* __restrict__ W3, unsigned short* __restrict__ T3,
    const float* __restrict__ W4, unsigned short* __restrict__ T4,
    const float* __restrict__ W5, unsigned short* __restrict__ T5)
{
    const int idx = blockIdx.x * 256 + threadIdx.x;
    if (blockIdx.y == 4) {            // W5: K=64 -> KS=2, N=256
        if (idx >= 2048) return;
        const int k8 = idx >> 8, n = idx & 255;
        const int ks = k8 >> 2, quad = k8 & 3;
        const int ntile = n >> 4, m_l = n & 15;
        unsigned short hi8[8], lo8[8];
        #pragma unroll
        for (int e = 0; e < 8; ++e) {
            const float v = W5[(k8 * 8 + e) * 256 + n];
            const unsigned short hi = f2bf(v);
            hi8[e] = hi; lo8[e] = f2bf(v - bf2f(hi));
        }
        const size_t b = (size_t)(((ks * 16 + ntile) * 2) * 64 + quad * 16 + m_l) * 8;
        *(uint4*)&T5[b]       = *(const uint4*)hi8;
        *(uint4*)&T5[b + 512] = *(const uint4*)lo8;
        return;
    }
    const float* W; unsigned short* T; int Kreal, nshift;
    switch (blockIdx.y) {
        case 0:  W = W1; T = T1; Kreal = 516; nshift = 9; break;
        case 1:  W = W2; T = T2; Kreal = 512; nshift = 8; break;
        case 2:  W = W3; T = T3; Kreal = 256; nshift = 7; break;
        default: W = W4; T = T4; Kreal = 128; nshift = 6; break;
    }
    const int N = 1 << nshift, NT = N >> 4;
    const int KS = (Kreal + 31) >> 5;
    if (idx >= N * KS * 4) return;
    const int k8 = idx >> nshift, n = idx & (N - 1);
    const int ks = k8 >> 2, quad = k8 & 3;
    const int ntile = n >> 4, m_l = n & 15;
    unsigned short t8[8];
    #pragma unroll
    for (int e = 0; e < 8; ++e) {
        const int k = k8 * 8 + e;
        t8[e] = (k < Kreal) ? f2bf(W[(size_t)k * N + n]) : (unsigned short)0;
    }
    *(uint4*)&T[(size_t)((ks * NT + ntile) * 64 + quad * 16 + m_l) * 8] = *(const uint4*)t8;
}

// ---- LDS layout (shorts) — BM=32 rows, R11-proven 68.6 KB -------------------
#define OFF_ZS   0
#define LD_ZS    552
#define OFF_H1   17664
#define LD_H1    520
#define OFF_H2   0
#define LD_H2    264
#define OFF_H3   17664
#define LD_H3    136
#define OFF_H4   8448
#define LD_H4    72
#define OFF_P    17664
#define LD_P     260
#define LDS_TOT  34304      // 68608 B -> 2 blocks/CU

// streamed MFMA layer pass: C[32 x NF*16] = lrelu(A @ W^T + bias) columns
// ntile0*16 .. (ntile0+NF)*16-1. ks-major packed Wt; DEP-deep asm load ring;
// bias pre-folded into acc; A-fragments prefetched one ks-group ahead.
template<int MR, int NF, int KSTEPS, int NT, int DEP>
__device__ __forceinline__ void layer_stream(
    unsigned short* lds, int offA, int lda, int offC, int ldc,
    const unsigned short* __restrict__ Wt,
    const float* __restrict__ bias, int ntile0, int rowbase, int lane)
{
    const int m_l = lane & 15, quad = lane >> 4;
    constexpr int NFR = NF * KSTEPS;
    static_assert(DEP <= NFR, "ring deeper than fragment stream");
    const unsigned short* __restrict__ Wb = Wt + ((size_t)ntile0 * 64 + lane) * 8;

    floatx4 acc[MR][NF];
    #pragma unroll
    for (int j = 0; j < NF; ++j) {
        const float bv = bias[ntile0 * 16 + j * 16 + m_l];
        #pragma unroll
        for (int m = 0; m < MR; ++m)
            acc[m][j] = (floatx4){bv, bv, bv, bv};
    }

    bf16x8 ring[DEP];
    #pragma unroll
    for (int f = 0; f < DEP; ++f) {
        const int g = (f < NFR) ? f : 0;
        ring[f] = gload(Wb + (size_t)((g / NF) * NT + (g % NF)) * 512);
    }
    bf16x8 a[MR], an[MR];
    #pragma unroll
    for (int m = 0; m < MR; ++m)
        a[m] = *(const bf16x8*)&lds[offA + (rowbase + m*16 + m_l) * lda + quad*8];
    #pragma unroll
    for (int f = 0; f < NFR; ++f) {
        const int ks = f / NF, j = f - ks * NF;
        if (j == 0 && ks + 1 < KSTEPS) {       // prefetch next ks-group's A
            #pragma unroll
            for (int m = 0; m < MR; ++m)
                an[m] = *(const bf16x8*)&lds[offA + (rowbase + m*16 + m_l) * lda + (ks+1)*32 + quad*8];
        }
        vwait<DEP - 1>(ring[f % DEP]);
        #pragma unroll
        for (int m = 0; m < MR; ++m)
            acc[m][j] = __builtin_amdgcn_mfma_f32_16x16x32_bf16(a[m], ring[f % DEP], acc[m][j], 0, 0, 0);
        const int nf2 = (f + DEP < NFR) ? f + DEP : 0;   // tail: dummy re-issues (L1-hot)
        ring[f % DEP] = gload(Wb + (size_t)((nf2 / NF) * NT + (nf2 % NF)) * 512);
        if (j == NF - 1 && ks + 1 < KSTEPS) {  // rotate prefetched A in
            #pragma unroll
            for (int m = 0; m < MR; ++m) a[m] = an[m];
        }
    }
    if constexpr (DEP == 8) drain8(ring); else drain4(ring);

    // epilogue: lrelu -> bf16 LDS (bias already in acc)
    #pragma unroll
    for (int j = 0; j < NF; ++j) {
        const int col = ntile0 * 16 + j * 16 + m_l;
        #pragma unroll
        for (int m = 0; m < MR; ++m)
            #pragma unroll
            for (int r = 0; r < 4; ++r) {
                float v = acc[m][j][r];
                v = v > 0.f ? v : 0.2f * v;
                lds[offC + (rowbase + m*16 + quad*4 + r) * ldc + col] = f2bf(v);
            }
    }
}

__global__ __launch_bounds__(512, 4) void fused_mlp_qp(
    const float* __restrict__ z, const float* __restrict__ bounds,
    const unsigned short* __restrict__ Wt1, const float* __restrict__ c1,
    const unsigned short* __restrict__ Wt2, const float* __restrict__ c2,
    const unsigned short* __restrict__ Wt3, const float* __restrict__ c3,
    const unsigned short* __restrict__ Wt4, const float* __restrict__ c4,
    const unsigned short* __restrict__ Wt5, const float* __restrict__ c5,
    float* __restrict__ out)
{
    __shared__ unsigned short lds[LDS_TOT];
    const int tid  = threadIdx.x;
    const int wid  = tid >> 6, lane = tid & 63;    // wid 0..7
    const int m_l  = lane & 15, quad = lane >> 4;
    const int bm   = blockIdx.x * 32;

    const float4 bnd = *(const float4*)bounds;

    // ---- stage ALL of z (32 rows; one latency; barrier drains everything) ---
    {
        const float4* __restrict__ zf = (const float4*)(z + (size_t)bm * 512);
        #pragma unroll
        for (int i = 0; i < 8; ++i) {
            const int f   = i * 512 + tid;
            const int row = f >> 7, c4i = f & 127;
            const float4 v = zf[f];
            unsigned short t4[4] = {f2bf(v.x), f2bf(v.y), f2bf(v.z), f2bf(v.w)};
            *(uint2*)&lds[OFF_ZS + row * LD_ZS + c4i * 4] = *(uint2*)t4;
        }
        if (tid < 160) {   // cols 512..551: bounds then zeros (32 rows x 5 u4)
            const int row = tid / 5, j = tid % 5;
            unsigned short t8[8] = {0,0,0,0,0,0,0,0};
            if (j == 0) { t8[0] = f2bf(bnd.x); t8[1] = f2bf(bnd.y);
                          t8[2] = f2bf(bnd.z); t8[3] = f2bf(bnd.w); }
            *(uint4*)&lds[OFF_ZS + row * LD_ZS + 512 + j * 8] = *(uint4*)t8;
        }
    }
    __syncthreads();

    // ---- streamed MFMA layers 1-4 (8-way N split, MR=2 -> M=32/fragment) ---
    layer_stream<2,2,17,32,8>(lds, OFF_ZS, LD_ZS, OFF_H1, LD_H1, Wt1, c1, wid*4,     0, lane);
    layer_stream<2,2,17,32,8>(lds, OFF_ZS, LD_ZS, OFF_H1, LD_H1, Wt1, c1, wid*4 + 2, 0, lane);
    __syncthreads();
    layer_stream<2,2,16,16,8>(lds, OFF_H1, LD_H1, OFF_H2, LD_H2, Wt2, c2, wid*2, 0, lane);
    __syncthreads();
    layer_stream<2,1, 8, 8,8>(lds, OFF_H2, LD_H2, OFF_H3, LD_H3, Wt3, c3, wid, 0, lane);
    __syncthreads();
    layer_stream<1,1, 4, 4,4>(lds, OFF_H3, LD_H3, OFF_H4, LD_H4, Wt4, c4, wid & 3, (wid >> 2) * 16, lane);
    __syncthreads();

    // ---- Layer 5: split-bf16 W5 stream; whole A-set loaded upfront ---------
    {
        const unsigned short* __restrict__ Wb5 = Wt5 + (size_t)wid * 2048 + (size_t)lane * 8;
        floatx4 acc[2][2];
        #pragma unroll
        for (int j = 0; j < 2; ++j) {
            const float bv = c5[wid * 32 + j * 16 + m_l];
            #pragma unroll
            for (int m = 0; m < 2; ++m)
                acc[m][j] = (floatx4){bv, bv, bv, bv};
        }
        auto w5off = [](int g) {   // g = ((ks*2 + j)*2 + hl) local to wave
            const int ks = g >> 2, rem = g & 3;
            return (size_t)ks * 16384 + (size_t)(rem >> 1) * 1024 + (size_t)(rem & 1) * 512;
        };
        bf16x8 ring[8];
        #pragma unroll
        for (int f = 0; f < 8; ++f) ring[f] = gload(Wb5 + w5off(f));
        bf16x8 a[2][2];
        #pragma unroll
        for (int ks = 0; ks < 2; ++ks)
            #pragma unroll
            for (int m = 0; m < 2; ++m)
                a[ks][m] = *(const bf16x8*)&lds[OFF_H4 + (m*16 + m_l) * LD_H4 + ks*32 + quad*8];
        #pragma unroll
        for (int f = 0; f < 8; ++f) {
            const int ks = f >> 2, rem = f & 3, j = rem >> 1;
            vwait<7>(ring[f]);
            #pragma unroll
            for (int m = 0; m < 2; ++m)
                acc[m][j] = __builtin_amdgcn_mfma_f32_16x16x32_bf16(a[ks][m], ring[f], acc[m][j], 0, 0, 0);
            ring[f] = gload(Wb5 + w5off(0));   // dummy keeps vmcnt exact
        }
        drain8(ring);

        float* __restrict__ p = (float*)&lds[OFF_P];
        #pragma unroll
        for (int j = 0; j < 2; ++j) {
            const int col = wid * 32 + j * 16 + m_l;
            #pragma unroll
            for (int m = 0; m < 2; ++m)
                #pragma unroll
                for (int r = 0; r < 4; ++r)
                    p[(m*16 + quad*4 + r) * LD_P + col] = acc[m][j][r];
        }
    }
    __syncthreads();

    // ---- QP: one row per wave-iteration, contiguous float4 LDS reads -------
    const float b0 = bnd.x, b1 = bnd.y, b2 = bnd.z, b3 = bnd.w;
    const float* __restrict__ p = (const float*)&lds[OFF_P];
    #pragma unroll
    for (int i = 0; i < 4; ++i) {
        const int row = i * 8 + wid;
        const float4 pv = *(const float4*)&p[row * LD_P + lane * 4];
        float xs, wo, ys, ho;
        {
            const float px = pv.x, pw = pv.z;
            const float x0 = fmaxf(px, b0);
            const float g0 = fmaxf(pw, 1.0f);
            const float t  = 0.5f * (b2 - px - pw);
            const float xl = fminf(fmaxf(px + t, b0), b2 - 1.0f);
            const bool over = (x0 + g0) > b2;
            const float x = over ? xl : x0;
            const float g = over ? (b2 - xl) : g0;
            xs = x; wo = x + g;
        }
        {
            const float py = pv.y, ph = pv.w;
            const float x0 = fmaxf(py, b1);
            const float g0 = fmaxf(ph, 1.0f);
            const float t  = 0.5f * (b3 - py - ph);
            const float xl = fminf(fmaxf(py + t, b1), b3 - 1.0f);
            const bool over = (x0 + g0) > b3;
            const float x = over ? xl : x0;
            const float g = over ? (b3 - xl) : g0;
            ys = x; ho = x + g;
        }
        float4 o; o.x = xs; o.y = ys; o.z = wo; o.w = ho;
        ((float4*)out)[(size_t)(bm + row) * 64 + lane] = o;
    }
}

extern "C" void kernel_launch(void* const* d_in, const int* in_sizes, int n_in,
                              void* d_out, int out_size, void* d_ws, size_t ws_size,
                              hipStream_t stream) {
    const float* z      = (const float*)d_in[0];
    const float* bounds = (const float*)d_in[1];
    const float* W1 = (const float*)d_in[2];
    const float* c1 = (const float*)d_in[3];
    const float* W2 = (const float*)d_in[4];
    const float* c2 = (const float*)d_in[5];
    const float* W3 = (const float*)d_in[6];
    const float* c3 = (const float*)d_in[7];
    const float* W4 = (const float*)d_in[8];
    const float* c4 = (const float*)d_in[9];
    const float* W5 = (const float*)d_in[10];
    const float* c5 = (const float*)d_in[11];
    float* out = (float*)d_out;

    unsigned short* ws  = (unsigned short*)d_ws;
    unsigned short* Wt1 = ws;               // 512x544 = 278528
    unsigned short* Wt2 = Wt1 + 278528;     // 256x512 = 131072
    unsigned short* Wt3 = Wt2 + 131072;     // 128x256 = 32768
    unsigned short* Wt4 = Wt3 + 32768;      //  64x128 =  8192
    unsigned short* Wt5 = Wt4 + 8192;       // 256x64x2 = 32768 (hi/lo)

    pack_wt<<<dim3(136, 5), 256, 0, stream>>>(
        W1, Wt1, W2, Wt2, W3, Wt3, W4, Wt4, W5, Wt5);
    fused_mlp_qp<<<dim3(MROWS / 32), 512, 0, stream>>>(
        z, bounds, Wt1, c1, Wt2, c2, Wt3, c3, Wt4, c4, Wt5, c5, out);
}

// Round 8
// 119.436 us; speedup vs baseline: 1.0742x; 1.0742x over previous
//
#include <hip/hip_runtime.h>

// ---------------------------------------------------------------------------
// CVX_Reasoning_Engine — Round 19: single-pass layer 1 (NF=4, DEP=16).
//   Ledger: traffic/2 = -4.2µs (R11->R15); traffic*2 = +8.2µs (R17->R18);
//   ILP/occupancy levers neutral. BM=64 @ 1 block/CU is the right point;
//   R18's 2-blocks/CU regression confirms traffic dominates barrier overlap.
//   R17's two-pass layer 1 was an artifact of the disproven pressure theory:
//   it doubles L1 A-fragment LDS reads (+68 ds_read_b128/wave) and pays a
//   mid-layer drain->refill latency. R16 proved DEP=16 + tied drain16 is
//   correct; merged NF=4 needs ~190 VGPR < 256 cap. Per-column accumulation
//   order unchanged -> bit-identical output.
// ---------------------------------------------------------------------------

#define MROWS 16384

typedef __attribute__((ext_vector_type(8))) short bf16x8;   // 8 bf16 = 4 VGPRs
typedef __attribute__((ext_vector_type(4))) float floatx4;

__device__ __forceinline__ unsigned short f2bf(float x) {
    union { float f; unsigned u; } c; c.f = x;
    unsigned r = c.u + 0x7fffu + ((c.u >> 16) & 1u);   // RNE
    return (unsigned short)(r >> 16);
}
__device__ __forceinline__ float bf2f(unsigned short b) {
    union { unsigned u; float f; } c; c.u = ((unsigned)b) << 16;
    return c.f;
}

// --- invisible-to-compiler 16B global load (1 KB/wave) ----------------------
__device__ __forceinline__ bf16x8 gload(const unsigned short* p) {
    bf16x8 r;
    asm volatile("global_load_dwordx4 %0, %1, off"
                 : "=&v"(r)
                 : "v"((unsigned long long)(size_t)p)
                 : "memory");
    return r;
}
// wait until <=IMM vmem outstanding. NO memory clobber: the "+v" tie carries
// the real dependence; LDS reads may be hoisted above the stall. (R17.)
template<int IMM>
__device__ __forceinline__ void vwait(bf16x8& v) {
    asm volatile("s_waitcnt vmcnt(%1)" : "+v"(v) : "n"(IMM));
}
// TIED drains: keep every ring register live until vmcnt(0) so regalloc
// cannot reassign a VGPR that an in-flight load will still write. (R15.)
__device__ __forceinline__ void drain16(bf16x8 (&r)[16]) {
    asm volatile("s_waitcnt vmcnt(0)"
                 : "+v"(r[0]),  "+v"(r[1]),  "+v"(r[2]),  "+v"(r[3]),
                   "+v"(r[4]),  "+v"(r[5]),  "+v"(r[6]),  "+v"(r[7]),
                   "+v"(r[8]),  "+v"(r[9]),  "+v"(r[10]), "+v"(r[11]),
                   "+v"(r[12]), "+v"(r[13]), "+v"(r[14]), "+v"(r[15])
                 :: "memory");
}
__device__ __forceinline__ void drain8(bf16x8 (&r)[8]) {
    asm volatile("s_waitcnt vmcnt(0)"
                 : "+v"(r[0]), "+v"(r[1]), "+v"(r[2]), "+v"(r[3]),
                   "+v"(r[4]), "+v"(r[5]), "+v"(r[6]), "+v"(r[7])
                 :: "memory");
}
__device__ __forceinline__ void drain4(bf16x8 (&r)[4]) {
    asm volatile("s_waitcnt vmcnt(0)"
                 : "+v"(r[0]), "+v"(r[1]), "+v"(r[2]), "+v"(r[3])
                 :: "memory");
}

// ---- pack weights -> ks-major fragment-ordered bf16 ------------------------
// W1..W4: T[((ks*NT + ntile)*64 + quad*16 + m_l)*8 + e],  NT = N/16.
// W5: split hi/lo interleaved: T5[(((ks*16 + ntile)*2 + hl)*64 + ...)*8 + e].
__global__ __launch_bounds__(256) void pack_wt(
    const float* __restrict__ W1, unsigned short* __restrict__ T1,
    const float* __restrict__ W2, unsigned short* __restrict__ T2,
    const float* __restrict__ W3, unsigned short* __restrict__ T3,
    const float* __restrict__ W4, unsigned short* __restrict__ T4,
    const float* __restrict__ W5, unsigned short* __restrict__ T5)
{
    const int idx = blockIdx.x * 256 + threadIdx.x;
    if (blockIdx.y == 4) {            // W5: K=64 -> KS=2, N=256
        if (idx >= 2048) return;
        const int k8 = idx >> 8, n = idx & 255;
        const int ks = k8 >> 2, quad = k8 & 3;
        const int ntile = n >> 4, m_l = n & 15;
        unsigned short hi8[8], lo8[8];
        #pragma unroll
        for (int e = 0; e < 8; ++e) {
            const float v = W5[(k8 * 8 + e) * 256 + n];
            const unsigned short hi = f2bf(v);
            hi8[e] = hi; lo8[e] = f2bf(v - bf2f(hi));
        }
        const size_t b = (size_t)(((ks * 16 + ntile) * 2) * 64 + quad * 16 + m_l) * 8;
        *(uint4*)&T5[b]       = *(const uint4*)hi8;
        *(uint4*)&T5[b + 512] = *(const uint4*)lo8;
        return;
    }
    const float* W; unsigned short* T; int Kreal, nshift;
    switch (blockIdx.y) {
        case 0:  W = W1; T = T1; Kreal = 516; nshift = 9; break;
        case 1:  W = W2; T = T2; Kreal = 512; nshift = 8; break;
        case 2:  W = W3; T = T3; Kreal = 256; nshift = 7; break;
        default: W = W4; T = T4; Kreal = 128; nshift = 6; break;
    }
    const int N = 1 << nshift, NT = N >> 4;
    const int KS = (Kreal + 31) >> 5;
    if (idx >= N * KS * 4) return;
    const int k8 = idx >> nshift, n = idx & (N - 1);
    const int ks = k8 >> 2, quad = k8 & 3;
    const int ntile = n >> 4, m_l = n & 15;
    unsigned short t8[8];
    #pragma unroll
    for (int e = 0; e < 8; ++e) {
        const int k = k8 * 8 + e;
        t8[e] = (k < Kreal) ? f2bf(W[(size_t)k * N + n]) : (unsigned short)0;
    }
    *(uint4*)&T[(size_t)((ks * NT + ntile) * 64 + quad * 16 + m_l) * 8] = *(const uint4*)t8;
}

// ---- LDS layout (shorts) — BM=64 rows ---------------------------------------
#define OFF_ZS   0
#define LD_ZS    552
#define OFF_H1   35328
#define LD_H1    520
#define OFF_H2   0
#define LD_H2    264
#define OFF_H3   16896
#define LD_H3    136
#define OFF_H4   25600
#define LD_H4    72
#define OFF_P    35328
#define LD_P     260
#define LDS_TOT  68608      // 137216 B <= 160 KiB

// streamed MFMA layer pass: C[64 x NF*16] = lrelu(A @ W^T + bias) columns
// ntile0*16 .. (ntile0+NF)*16-1. ks-major packed Wt; DEP-deep asm load ring;
// bias pre-folded into acc; A-fragments prefetched one ks-group ahead.
template<int MR, int NF, int KSTEPS, int NT, int DEP>
__device__ __forceinline__ void layer_stream(
    unsigned short* lds, int offA, int lda, int offC, int ldc,
    const unsigned short* __restrict__ Wt,
    const float* __restrict__ bias, int ntile0, int rowbase, int lane)
{
    const int m_l = lane & 15, quad = lane >> 4;
    constexpr int NFR = NF * KSTEPS;
    static_assert(DEP <= NFR, "ring deeper than fragment stream");
    const unsigned short* __restrict__ Wb = Wt + ((size_t)ntile0 * 64 + lane) * 8;

    floatx4 acc[MR][NF];
    #pragma unroll
    for (int j = 0; j < NF; ++j) {
        const float bv = bias[ntile0 * 16 + j * 16 + m_l];
        #pragma unroll
        for (int m = 0; m < MR; ++m)
            acc[m][j] = (floatx4){bv, bv, bv, bv};
    }

    bf16x8 ring[DEP];
    #pragma unroll
    for (int f = 0; f < DEP; ++f) {
        const int g = (f < NFR) ? f : 0;
        ring[f] = gload(Wb + (size_t)((g / NF) * NT + (g % NF)) * 512);
    }
    bf16x8 a[MR], an[MR];
    #pragma unroll
    for (int m = 0; m < MR; ++m)
        a[m] = *(const bf16x8*)&lds[offA + (rowbase + m*16 + m_l) * lda + quad*8];
    #pragma unroll
    for (int f = 0; f < NFR; ++f) {
        const int ks = f / NF, j = f - ks * NF;
        if (j == 0 && ks + 1 < KSTEPS) {       // prefetch next ks-group's A
            #pragma unroll
            for (int m = 0; m < MR; ++m)
                an[m] = *(const bf16x8*)&lds[offA + (rowbase + m*16 + m_l) * lda + (ks+1)*32 + quad*8];
        }
        vwait<DEP - 1>(ring[f % DEP]);
        #pragma unroll
        for (int m = 0; m < MR; ++m)
            acc[m][j] = __builtin_amdgcn_mfma_f32_16x16x32_bf16(a[m], ring[f % DEP], acc[m][j], 0, 0, 0);
        const int nf2 = (f + DEP < NFR) ? f + DEP : 0;   // tail: dummy re-issues (L1-hot)
        ring[f % DEP] = gload(Wb + (size_t)((nf2 / NF) * NT + (nf2 % NF)) * 512);
        if (j == NF - 1 && ks + 1 < KSTEPS) {  // rotate prefetched A in
            #pragma unroll
            for (int m = 0; m < MR; ++m) a[m] = an[m];
        }
    }
    if constexpr (DEP == 16) drain16(ring);
    else if constexpr (DEP == 8) drain8(ring);
    else drain4(ring);

    // epilogue: lrelu -> bf16 LDS (bias already in acc)
    #pragma unroll
    for (int j = 0; j < NF; ++j) {
        const int col = ntile0 * 16 + j * 16 + m_l;
        #pragma unroll
        for (int m = 0; m < MR; ++m)
            #pragma unroll
            for (int r = 0; r < 4; ++r) {
                float v = acc[m][j][r];
                v = v > 0.f ? v : 0.2f * v;
                lds[offC + (rowbase + m*16 + quad*4 + r) * ldc + col] = f2bf(v);
            }
    }
}

__global__ __launch_bounds__(512, 2) void fused_mlp_qp(
    const float* __restrict__ z, const float* __restrict__ bounds,
    const unsigned short* __restrict__ Wt1, const float* __restrict__ c1,
    const unsigned short* __restrict__ Wt2, const float* __restrict__ c2,
    const unsigned short* __restrict__ Wt3, const float* __restrict__ c3,
    const unsigned short* __restrict__ Wt4, const float* __restrict__ c4,
    const unsigned short* __restrict__ Wt5, const float* __restrict__ c5,
    float* __restrict__ out)
{
    __shared__ unsigned short lds[LDS_TOT];
    const int tid  = threadIdx.x;
    const int wid  = tid >> 6, lane = tid & 63;    // wid 0..7
    const int m_l  = lane & 15, quad = lane >> 4;
    const int bm   = blockIdx.x * 64;

    const float4 bnd = *(const float4*)bounds;

    // ---- stage ALL of z (64 rows; one latency; barrier drains everything) ---
    {
        const float4* __restrict__ zf = (const float4*)(z + (size_t)bm * 512);
        #pragma unroll
        for (int i = 0; i < 16; ++i) {
            const int f   = i * 512 + tid;
            const int row = f >> 7, c4i = f & 127;
            const float4 v = zf[f];
            unsigned short t4[4] = {f2bf(v.x), f2bf(v.y), f2bf(v.z), f2bf(v.w)};
            *(uint2*)&lds[OFF_ZS + row * LD_ZS + c4i * 4] = *(uint2*)t4;
        }
        if (tid < 320) {   // cols 512..551: bounds then zeros (64 rows x 5 u4)
            const int row = tid / 5, j = tid % 5;
            unsigned short t8[8] = {0,0,0,0,0,0,0,0};
            if (j == 0) { t8[0] = f2bf(bnd.x); t8[1] = f2bf(bnd.y);
                          t8[2] = f2bf(bnd.z); t8[3] = f2bf(bnd.w); }
            *(uint4*)&lds[OFF_ZS + row * LD_ZS + 512 + j * 8] = *(uint4*)t8;
        }
    }
    __syncthreads();

    // ---- streamed MFMA layers 1-4 (8-way N split, each wave does M=64) -----
    layer_stream<4,4,17,32,16>(lds, OFF_ZS, LD_ZS, OFF_H1, LD_H1, Wt1, c1, wid*4, 0, lane);
    __syncthreads();
    layer_stream<4,2,16,16,16>(lds, OFF_H1, LD_H1, OFF_H2, LD_H2, Wt2, c2, wid*2, 0, lane);
    __syncthreads();
    layer_stream<4,1, 8, 8, 8>(lds, OFF_H2, LD_H2, OFF_H3, LD_H3, Wt3, c3, wid, 0, lane);
    __syncthreads();
    layer_stream<2,1, 4, 4, 4>(lds, OFF_H3, LD_H3, OFF_H4, LD_H4, Wt4, c4, wid & 3, (wid >> 2) * 32, lane);
    __syncthreads();

    // ---- Layer 5: split-bf16 W5 stream; whole A-set loaded upfront ---------
    {
        const unsigned short* __restrict__ Wb5 = Wt5 + (size_t)wid * 2048 + (size_t)lane * 8;
        floatx4 acc[4][2];
        #pragma unroll
        for (int j = 0; j < 2; ++j) {
            const float bv = c5[wid * 32 + j * 16 + m_l];
            #pragma unroll
            for (int m = 0; m < 4; ++m)
                acc[m][j] = (floatx4){bv, bv, bv, bv};
        }
        auto w5off = [](int g) {   // g = ((ks*2 + j)*2 + hl) local to wave
            const int ks = g >> 2, rem = g & 3;
            return (size_t)ks * 16384 + (size_t)(rem >> 1) * 1024 + (size_t)(rem & 1) * 512;
        };
        bf16x8 ring[8];
        #pragma unroll
        for (int f = 0; f < 8; ++f) ring[f] = gload(Wb5 + w5off(f));
        bf16x8 a[2][4];
        #pragma unroll
        for (int ks = 0; ks < 2; ++ks)
            #pragma unroll
            for (int m = 0; m < 4; ++m)
                a[ks][m] = *(const bf16x8*)&lds[OFF_H4 + (m*16 + m_l) * LD_H4 + ks*32 + quad*8];
        #pragma unroll
        for (int f = 0; f < 8; ++f) {
            const int ks = f >> 2, rem = f & 3, j = rem >> 1;
            vwait<7>(ring[f]);
            #pragma unroll
            for (int m = 0; m < 4; ++m)
                acc[m][j] = __builtin_amdgcn_mfma_f32_16x16x32_bf16(a[ks][m], ring[f], acc[m][j], 0, 0, 0);
            ring[f] = gload(Wb5 + w5off(0));   // dummy keeps vmcnt exact
        }
        drain8(ring);

        float* __restrict__ p = (float*)&lds[OFF_P];
        #pragma unroll
        for (int j = 0; j < 2; ++j) {
            const int col = wid * 32 + j * 16 + m_l;
            #pragma unroll
            for (int m = 0; m < 4; ++m)
                #pragma unroll
                for (int r = 0; r < 4; ++r)
                    p[(m*16 + quad*4 + r) * LD_P + col] = acc[m][j][r];
        }
    }
    __syncthreads();

    // ---- QP: one row per wave-iteration, contiguous float4 LDS reads -------
    const float b0 = bnd.x, b1 = bnd.y, b2 = bnd.z, b3 = bnd.w;
    const float* __restrict__ p = (const float*)&lds[OFF_P];
    #pragma unroll
    for (int i = 0; i < 8; ++i) {
        const int row = i * 8 + wid;
        const float4 pv = *(const float4*)&p[row * LD_P + lane * 4];
        float xs, wo, ys, ho;
        {
            const float px = pv.x, pw = pv.z;
            const float x0 = fmaxf(px, b0);
            const float g0 = fmaxf(pw, 1.0f);
            const float t  = 0.5f * (b2 - px - pw);
            const float xl = fminf(fmaxf(px + t, b0), b2 - 1.0f);
            const bool over = (x0 + g0) > b2;
            const float x = over ? xl : x0;
            const float g = over ? (b2 - xl) : g0;
            xs = x; wo = x + g;
        }
        {
            const float py = pv.y, ph = pv.w;
            const float x0 = fmaxf(py, b1);
            const float g0 = fmaxf(ph, 1.0f);
            const float t  = 0.5f * (b3 - py - ph);
            const float xl = fminf(fmaxf(py + t, b1), b3 - 1.0f);
            const bool over = (x0 + g0) > b3;
            const float x = over ? xl : x0;
            const float g = over ? (b3 - xl) : g0;
            ys = x; ho = x + g;
        }
        float4 o; o.x = xs; o.y = ys; o.z = wo; o.w = ho;
        ((float4*)out)[(size_t)(bm + row) * 64 + lane] = o;
    }
}

extern "C" void kernel_launch(void* const* d_in, const int* in_sizes, int n_in,
                              void* d_out, int out_size, void* d_ws, size_t ws_size,
                              hipStream_t stream) {
    const float* z      = (const float*)d_in[0];
    const float* bounds = (const float*)d_in[1];
    const float* W1 = (const float*)d_in[2];
    const float* c1 = (const float*)d_in[3];
    const float* W2 = (const float*)d_in[4];
    const float* c2 = (const float*)d_in[5];
    const float* W3 = (const float*)d_in[6];
    const float* c3 = (const float*)d_in[7];
    const float* W4 = (const float*)d_in[8];
    const float* c4 = (const float*)d_in[9];
    const float* W5 = (const float*)d_in[10];
    const float* c5 = (const float*)d_in[11];
    float* out = (float*)d_out;

    unsigned short* ws  = (unsigned short*)d_ws;
    unsigned short* Wt1 = ws;               // 512x544 = 278528
    unsigned short* Wt2 = Wt1 + 278528;     // 256x512 = 131072
    unsigned short* Wt3 = Wt2 + 131072;     // 128x256 = 32768
    unsigned short* Wt4 = Wt3 + 32768;      //  64x128 =  8192
    unsigned short* Wt5 = Wt4 + 8192;       // 256x64x2 = 32768 (hi/lo)

    pack_wt<<<dim3(136, 5), 256, 0, stream>>>(
        W1, Wt1, W2, Wt2, W3, Wt3, W4, Wt4, W5, Wt5);
    fused_mlp_qp<<<dim3(MROWS / 64), 512, 0, stream>>>(
        z, bounds, Wt1, c1, Wt2, c2, Wt3, c3, Wt4, c4, Wt5, c5, out);
}

// Round 9
// 115.576 us; speedup vs baseline: 1.1101x; 1.0334x over previous
//
#include <hip/hip_runtime.h>

// ---------------------------------------------------------------------------
// CVX_Reasoning_Engine — Round 20: ONE persistent ring across all 5 layers.
//   R19 ledger: traffic ±linear, pass-merge -0.6µs, ILP/occ neutral. The
//   untouched structural stall: per-layer drain16 -> __syncthreads (compiler
//   emits vmcnt(0)) -> ring refill = ~2 exposed L2 latencies per boundary,
//   5 boundaries, 1 block/CU (nothing covers them). R20: flat 120-fragment
//   stream (L1:68 L2:32 L3:8 L4:4 L5:8) through one 16-slot ring; consume g
//   waits vwait<15> on slot g&15 and re-issues frag g+16 via cross-layer
//   frag_addr; raw lgkmcnt-only barriers between layers (weights stay in
//   flight); biases staged to LDS so the MLP region has zero compiler VMEM
//   (exact vmcnt); ring filled before z-staging (fill hides under HBM reads;
//   older-invisible-loads + in-order retirement keep compiler waits safe);
//   single drain16 at stream end. Accumulation order unchanged.
// ---------------------------------------------------------------------------

#define MROWS 16384

typedef __attribute__((ext_vector_type(8))) short bf16x8;   // 8 bf16 = 4 VGPRs
typedef __attribute__((ext_vector_type(4))) float floatx4;

__device__ __forceinline__ unsigned short f2bf(float x) {
    union { float f; unsigned u; } c; c.f = x;
    unsigned r = c.u + 0x7fffu + ((c.u >> 16) & 1u);   // RNE
    return (unsigned short)(r >> 16);
}
__device__ __forceinline__ float bf2f(unsigned short b) {
    union { unsigned u; float f; } c; c.u = ((unsigned)b) << 16;
    return c.f;
}

// --- invisible-to-compiler 16B global load (1 KB/wave) ----------------------
__device__ __forceinline__ bf16x8 gload(const unsigned short* p) {
    bf16x8 r;
    asm volatile("global_load_dwordx4 %0, %1, off"
                 : "=&v"(r)
                 : "v"((unsigned long long)(size_t)p)
                 : "memory");
    return r;
}
// wait until <=IMM vmem outstanding. NO memory clobber: the "+v" tie carries
// the real dependence (R17-proven).
template<int IMM>
__device__ __forceinline__ void vwait(bf16x8& v) {
    asm volatile("s_waitcnt vmcnt(%1)" : "+v"(v) : "n"(IMM));
}
// TIED drain: keeps every ring register live until vmcnt(0). (R15-proven.)
__device__ __forceinline__ void drain16(bf16x8 (&r)[16]) {
    asm volatile("s_waitcnt vmcnt(0)"
                 : "+v"(r[0]),  "+v"(r[1]),  "+v"(r[2]),  "+v"(r[3]),
                   "+v"(r[4]),  "+v"(r[5]),  "+v"(r[6]),  "+v"(r[7]),
                   "+v"(r[8]),  "+v"(r[9]),  "+v"(r[10]), "+v"(r[11]),
                   "+v"(r[12]), "+v"(r[13]), "+v"(r[14]), "+v"(r[15])
                 :: "memory");
}
// LDS-only barrier: waits ds ops, NOT vmem — weight loads stay in flight.
__device__ __forceinline__ void lds_barrier() {
    asm volatile("s_waitcnt lgkmcnt(0)\n\ts_barrier" ::: "memory");
}

// ---- pack weights -> ks-major fragment-ordered bf16 ------------------------
// W1..W4: T[((ks*NT + ntile)*64 + quad*16 + m_l)*8 + e],  NT = N/16.
// W5: split hi/lo interleaved: T5[(((ks*16 + ntile)*2 + hl)*64 + ...)*8 + e].
__global__ __launch_bounds__(256) void pack_wt(
    const float* __restrict__ W1, unsigned short* __restrict__ T1,
    const float* __restrict__ W2, unsigned short* __restrict__ T2,
    const float* __restrict__ W3, unsigned short* __restrict__ T3,
    const float* __restrict__ W4, unsigned short* __restrict__ T4,
    const float* __restrict__ W5, unsigned short* __restrict__ T5)
{
    const int idx = blockIdx.x * 256 + threadIdx.x;
    if (blockIdx.y == 4) {            // W5: K=64 -> KS=2, N=256
        if (idx >= 2048) return;
        const int k8 = idx >> 8, n = idx & 255;
        const int ks = k8 >> 2, quad = k8 & 3;
        const int ntile = n >> 4, m_l = n & 15;
        unsigned short hi8[8], lo8[8];
        #pragma unroll
        for (int e = 0; e < 8; ++e) {
            const float v = W5[(k8 * 8 + e) * 256 + n];
            const unsigned short hi = f2bf(v);
            hi8[e] = hi; lo8[e] = f2bf(v - bf2f(hi));
        }
        const size_t b = (size_t)(((ks * 16 + ntile) * 2) * 64 + quad * 16 + m_l) * 8;
        *(uint4*)&T5[b]       = *(const uint4*)hi8;
        *(uint4*)&T5[b + 512] = *(const uint4*)lo8;
        return;
    }
    const float* W; unsigned short* T; int Kreal, nshift;
    switch (blockIdx.y) {
        case 0:  W = W1; T = T1; Kreal = 516; nshift = 9; break;
        case 1:  W = W2; T = T2; Kreal = 512; nshift = 8; break;
        case 2:  W = W3; T = T3; Kreal = 256; nshift = 7; break;
        default: W = W4; T = T4; Kreal = 128; nshift = 6; break;
    }
    const int N = 1 << nshift, NT = N >> 4;
    const int KS = (Kreal + 31) >> 5;
    if (idx >= N * KS * 4) return;
    const int k8 = idx >> nshift, n = idx & (N - 1);
    const int ks = k8 >> 2, quad = k8 & 3;
    const int ntile = n >> 4, m_l = n & 15;
    unsigned short t8[8];
    #pragma unroll
    for (int e = 0; e < 8; ++e) {
        const int k = k8 * 8 + e;
        t8[e] = (k < Kreal) ? f2bf(W[(size_t)k * N + n]) : (unsigned short)0;
    }
    *(uint4*)&T[(size_t)((ks * NT + ntile) * 64 + quad * 16 + m_l) * 8] = *(const uint4*)t8;
}

// ---- LDS layout (shorts) — BM=64 rows ---------------------------------------
#define OFF_ZS   0
#define LD_ZS    552
#define OFF_H1   35328
#define LD_H1    520
#define OFF_H2   0
#define LD_H2    264
#define OFF_H3   16896
#define LD_H3    136
#define OFF_H4   25600
#define LD_H4    72
#define OFF_P    35328
#define LD_P     260
#define OFF_BF   68608      // bias floats area (short offset; 4B-aligned)
#define LDS_TOT  71040      // 142080 B <= 160 KiB (1 block/CU)

// per-wave fragment bases for the flat 120-fragment stream
struct WPlan {
    const unsigned short* b0; const unsigned short* b1;
    const unsigned short* b2; const unsigned short* b3;
    const unsigned short* b4;
};
// flat stream: L1 g=[0,68) L2 [68,100) L3 [100,108) L4 [108,112) L5 [112,120)
__device__ __forceinline__ const unsigned short* frag_addr(const WPlan& P, int g) {
    if (g >= 120) g = 0;                                   // tail dummies
    if (g < 68)  { const int f = g;       return P.b0 + (size_t)((f >> 2) * 32 + (f & 3)) * 512; }
    if (g < 100) { const int f = g - 68;  return P.b1 + (size_t)((f >> 1) * 16 + (f & 1)) * 512; }
    if (g < 108) { const int f = g - 100; return P.b2 + (size_t)(f * 8) * 512; }
    if (g < 112) { const int f = g - 108; return P.b3 + (size_t)(f * 4) * 512; }
    { const int f = g - 112; const int ks = f >> 2, rem = f & 3;
      return P.b4 + (size_t)ks * 16384 + (size_t)(rem >> 1) * 1024 + (size_t)(rem & 1) * 512; }
}

// one MLP layer as a section of the persistent ring stream.
// Consumes g=G0..G0+NF*KSTEPS-1; each consume re-issues frag g+16.
template<int MR, int NF, int KSTEPS, int G0>
__device__ __forceinline__ void section(
    bf16x8 (&ring)[16], unsigned short* lds, const WPlan& P,
    int offA, int lda, int offC, int ldc,
    const float* bias, int ntile0, int rowbase, int lane)
{
    const int m_l = lane & 15, quad = lane >> 4;
    constexpr int NFR = NF * KSTEPS;
    floatx4 acc[MR][NF];
    #pragma unroll
    for (int j = 0; j < NF; ++j) {
        const float bv = bias[ntile0 * 16 + j * 16 + m_l];   // LDS read (lgkm)
        #pragma unroll
        for (int m = 0; m < MR; ++m)
            acc[m][j] = (floatx4){bv, bv, bv, bv};
    }
    bf16x8 a[MR], an[MR];
    #pragma unroll
    for (int m = 0; m < MR; ++m)
        a[m] = *(const bf16x8*)&lds[offA + (rowbase + m*16 + m_l) * lda + quad*8];
    #pragma unroll
    for (int f = 0; f < NFR; ++f) {
        const int ks = f / NF, j = f - ks * NF, g = G0 + f;
        if (j == 0 && ks + 1 < KSTEPS) {       // prefetch next ks-group's A
            #pragma unroll
            for (int m = 0; m < MR; ++m)
                an[m] = *(const bf16x8*)&lds[offA + (rowbase + m*16 + m_l) * lda + (ks+1)*32 + quad*8];
        }
        vwait<15>(ring[g & 15]);
        #pragma unroll
        for (int m = 0; m < MR; ++m)
            acc[m][j] = __builtin_amdgcn_mfma_f32_16x16x32_bf16(a[m], ring[g & 15], acc[m][j], 0, 0, 0);
        ring[g & 15] = gload(frag_addr(P, g + 16));
        if (j == NF - 1 && ks + 1 < KSTEPS) {  // rotate prefetched A in
            #pragma unroll
            for (int m = 0; m < MR; ++m) a[m] = an[m];
        }
    }
    // epilogue: lrelu -> bf16 LDS (bias already in acc)
    #pragma unroll
    for (int j = 0; j < NF; ++j) {
        const int col = ntile0 * 16 + j * 16 + m_l;
        #pragma unroll
        for (int m = 0; m < MR; ++m)
            #pragma unroll
            for (int r = 0; r < 4; ++r) {
                float v = acc[m][j][r];
                v = v > 0.f ? v : 0.2f * v;
                lds[offC + (rowbase + m*16 + quad*4 + r) * ldc + col] = f2bf(v);
            }
    }
}

__global__ __launch_bounds__(512, 2) void fused_mlp_qp(
    const float* __restrict__ z, const float* __restrict__ bounds,
    const unsigned short* __restrict__ Wt1, const float* __restrict__ c1,
    const unsigned short* __restrict__ Wt2, const float* __restrict__ c2,
    const unsigned short* __restrict__ Wt3, const float* __restrict__ c3,
    const unsigned short* __restrict__ Wt4, const float* __restrict__ c4,
    const unsigned short* __restrict__ Wt5, const float* __restrict__ c5,
    float* __restrict__ out)
{
    __shared__ unsigned short lds[LDS_TOT];
    const int tid  = threadIdx.x;
    const int wid  = tid >> 6, lane = tid & 63;    // wid 0..7
    const int m_l  = lane & 15, quad = lane >> 4;
    const int bm   = blockIdx.x * 64;

    const float4 bnd = *(const float4*)bounds;

    // ---- per-wave fragment plan + ring fill (issued FIRST: older-invisible
    // loads make all later compiler vmem waits conservative; fill latency
    // hides under the z/bias staging HBM reads) ------------------------------
    WPlan P;
    P.b0 = Wt1 + ((size_t)(wid * 4) * 64 + lane) * 8;
    P.b1 = Wt2 + ((size_t)(wid * 2) * 64 + lane) * 8;
    P.b2 = Wt3 + ((size_t)wid * 64 + lane) * 8;
    P.b3 = Wt4 + ((size_t)(wid & 3) * 64 + lane) * 8;
    P.b4 = Wt5 + (size_t)wid * 2048 + (size_t)lane * 8;

    bf16x8 ring[16];
    #pragma unroll
    for (int f = 0; f < 16; ++f) ring[f] = gload(frag_addr(P, f));

    // ---- stage z (64 rows) + biases (1216 floats) to LDS -------------------
    {
        const float4* __restrict__ zf = (const float4*)(z + (size_t)bm * 512);
        #pragma unroll
        for (int i = 0; i < 16; ++i) {
            const int f   = i * 512 + tid;
            const int row = f >> 7, c4i = f & 127;
            const float4 v = zf[f];
            unsigned short t4[4] = {f2bf(v.x), f2bf(v.y), f2bf(v.z), f2bf(v.w)};
            *(uint2*)&lds[OFF_ZS + row * LD_ZS + c4i * 4] = *(uint2*)t4;
        }
        if (tid < 320) {   // cols 512..551: bounds then zeros (64 rows x 5 u4)
            const int row = tid / 5, j = tid % 5;
            unsigned short t8[8] = {0,0,0,0,0,0,0,0};
            if (j == 0) { t8[0] = f2bf(bnd.x); t8[1] = f2bf(bnd.y);
                          t8[2] = f2bf(bnd.z); t8[3] = f2bf(bnd.w); }
            *(uint4*)&lds[OFF_ZS + row * LD_ZS + 512 + j * 8] = *(uint4*)t8;
        }
        float* bf = (float*)&lds[OFF_BF];
        for (int i = tid; i < 1216; i += 512) {
            float v;
            if      (i < 512)  v = c1[i];
            else if (i < 768)  v = c2[i - 512];
            else if (i < 896)  v = c3[i - 768];
            else if (i < 960)  v = c4[i - 896];
            else               v = c5[i - 960];
            bf[i] = v;
        }
    }
    lds_barrier();

    // ---- MLP: one persistent ring, LDS-only barriers between layers --------
    const float* bf = (const float*)&lds[OFF_BF];
    section<4,4,17,  0>(ring, lds, P, OFF_ZS, LD_ZS, OFF_H1, LD_H1, bf,       wid*4, 0, lane);
    lds_barrier();
    section<4,2,16, 68>(ring, lds, P, OFF_H1, LD_H1, OFF_H2, LD_H2, bf + 512, wid*2, 0, lane);
    lds_barrier();
    section<4,1, 8,100>(ring, lds, P, OFF_H2, LD_H2, OFF_H3, LD_H3, bf + 768, wid, 0, lane);
    lds_barrier();
    section<2,1, 4,108>(ring, lds, P, OFF_H3, LD_H3, OFF_H4, LD_H4, bf + 896, wid & 3, (wid >> 2) * 32, lane);
    lds_barrier();

    // ---- Layer 5 (g=112..119): split-bf16 hi/lo, whole A-set upfront -------
    {
        floatx4 acc[4][2];
        #pragma unroll
        for (int j = 0; j < 2; ++j) {
            const float bv = bf[960 + wid * 32 + j * 16 + m_l];
            #pragma unroll
            for (int m = 0; m < 4; ++m)
                acc[m][j] = (floatx4){bv, bv, bv, bv};
        }
        bf16x8 a[2][4];
        #pragma unroll
        for (int ks = 0; ks < 2; ++ks)
            #pragma unroll
            for (int m = 0; m < 4; ++m)
                a[ks][m] = *(const bf16x8*)&lds[OFF_H4 + (m*16 + m_l) * LD_H4 + ks*32 + quad*8];
        #pragma unroll
        for (int f = 0; f < 8; ++f) {
            const int ks = f >> 2, rem = f & 3, j = rem >> 1, g = 112 + f;
            vwait<15>(ring[g & 15]);
            #pragma unroll
            for (int m = 0; m < 4; ++m)
                acc[m][j] = __builtin_amdgcn_mfma_f32_16x16x32_bf16(a[ks][m], ring[g & 15], acc[m][j], 0, 0, 0);
            ring[g & 15] = gload(frag_addr(P, g + 16));   // dummies keep count
        }
        drain16(ring);

        float* __restrict__ p = (float*)&lds[OFF_P];
        #pragma unroll
        for (int j = 0; j < 2; ++j) {
            const int col = wid * 32 + j * 16 + m_l;
            #pragma unroll
            for (int m = 0; m < 4; ++m)
                #pragma unroll
                for (int r = 0; r < 4; ++r)
                    p[(m*16 + quad*4 + r) * LD_P + col] = acc[m][j][r];
        }
    }
    lds_barrier();

    // ---- QP: one row per wave-iteration, contiguous float4 LDS reads -------
    const float b0 = bnd.x, b1 = bnd.y, b2 = bnd.z, b3 = bnd.w;
    const float* __restrict__ p = (const float*)&lds[OFF_P];
    #pragma unroll
    for (int i = 0; i < 8; ++i) {
        const int row = i * 8 + wid;
        const float4 pv = *(const float4*)&p[row * LD_P + lane * 4];
        float xs, wo, ys, ho;
        {
            const float px = pv.x, pw = pv.z;
            const float x0 = fmaxf(px, b0);
            const float g0 = fmaxf(pw, 1.0f);
            const float t  = 0.5f * (b2 - px - pw);
            const float xl = fminf(fmaxf(px + t, b0), b2 - 1.0f);
            const bool over = (x0 + g0) > b2;
            const float x = over ? xl : x0;
            const float g = over ? (b2 - xl) : g0;
            xs = x; wo = x + g;
        }
        {
            const float py = pv.y, ph = pv.w;
            const float x0 = fmaxf(py, b1);
            const float g0 = fmaxf(ph, 1.0f);
            const float t  = 0.5f * (b3 - py - ph);
            const float xl = fminf(fmaxf(py + t, b1), b3 - 1.0f);
            const bool over = (x0 + g0) > b3;
            const float x = over ? xl : x0;
            const float g = over ? (b3 - xl) : g0;
            ys = x; ho = x + g;
        }
        float4 o; o.x = xs; o.y = ys; o.z = wo; o.w = ho;
        ((float4*)out)[(size_t)(bm + row) * 64 + lane] = o;
    }
}

extern "C" void kernel_launch(void* const* d_in, const int* in_sizes, int n_in,
                              void* d_out, int out_size, void* d_ws, size_t ws_size,
                              hipStream_t stream) {
    const float* z      = (const float*)d_in[0];
    const float* bounds = (const float*)d_in[1];
    const float* W1 = (const float*)d_in[2];
    const float* c1 = (const float*)d_in[3];
    const float* W2 = (const float*)d_in[4];
    const float* c2 = (const float*)d_in[5];
    const float* W3 = (const float*)d_in[6];
    const float* c3 = (const float*)d_in[7];
    const float* W4 = (const float*)d_in[8];
    const float* c4 = (const float*)d_in[9];
    const float* W5 = (const float*)d_in[10];
    const float* c5 = (const float*)d_in[11];
    float* out = (float*)d_out;

    unsigned short* ws  = (unsigned short*)d_ws;
    unsigned short* Wt1 = ws;               // 512x544 = 278528
    unsigned short* Wt2 = Wt1 + 278528;     // 256x512 = 131072
    unsigned short* Wt3 = Wt2 + 131072;     // 128x256 = 32768
    unsigned short* Wt4 = Wt3 + 32768;      //  64x128 =  8192
    unsigned short* Wt5 = Wt4 + 8192;       // 256x64x2 = 32768 (hi/lo)

    pack_wt<<<dim3(136, 5), 256, 0, stream>>>(
        W1, Wt1, W2, Wt2, W3, Wt3, W4, Wt4, W5, Wt5);
    fused_mlp_qp<<<dim3(MROWS / 64), 512, 0, stream>>>(
        z, bounds, Wt1, c1, Wt2, c2, Wt3, c3, Wt4, c4, Wt5, c5, out);
}